// Round 9
// baseline (271.138 us; speedup 1.0000x reference)
//
#include <hip/hip_runtime.h>
#include <hip/hip_bf16.h>

#define NEG_SLOPE 0.2f

typedef __attribute__((ext_vector_type(8))) short bf16x8;
typedef __attribute__((ext_vector_type(4))) float f32x4;

__device__ __forceinline__ float lrelu(float v) { return v > 0.0f ? v : NEG_SLOPE * v; }

__device__ __forceinline__ unsigned bf16pair(float a, float b) {
    unsigned ua = __float_as_uint(a), ub = __float_as_uint(b);
    ua = (ua + 0x7FFFu + ((ua >> 16) & 1u)) >> 16;
    ub = (ub + 0x7FFFu + ((ub >> 16) & 1u)) >> 16;
    return ua | (ub << 16);
}

// async global->LDS, 16B per lane; LDS dest is wave-uniform base + lane*16
__device__ __forceinline__ void gload16(const void* g, void* l) {
    __builtin_amdgcn_global_load_lds(
        (const __attribute__((address_space(1))) unsigned*)g,
        (__attribute__((address_space(3))) unsigned*)l, 16, 0, 0);
}

// ---------------- prep: x->xb bf16, W->Wt bf16 transposed, deg histogram ----
__global__ __launch_bounds__(256) void k_prep(const float* __restrict__ x,
                                              const float* __restrict__ W,
                                              const int* __restrict__ ei,
                                              unsigned* __restrict__ deg,
                                              unsigned* __restrict__ xb,
                                              unsigned short* __restrict__ Wt,
                                              int N, int E) {
    int gid = blockIdx.x * 256 + threadIdx.x;
    int gsz = gridDim.x * 256;
    int nf4 = N * 32;
    for (int i = gid; i < nf4; i += gsz) {
        float4 f = ((const float4*)x)[i];
        uint2 u;
        u.x = bf16pair(f.x, f.y);
        u.y = bf16pair(f.z, f.w);
        ((uint2*)xb)[i] = u;
    }
    if (gid < 16384) {
        int col = gid >> 7, k = gid & 127;
        float v = W[(size_t)k * 128 + col];
        unsigned u = __float_as_uint(v);
        u = (u + 0x7FFFu + ((u >> 16) & 1u)) >> 16;
        Wt[col * 128 + k] = (unsigned short)u;
    }
    for (int i = gid; i < E; i += gsz)
        atomicAdd(&deg[ei[(size_t)E + i]], 1u);
}

// ---------------- MFMA GEMM: h = xb @ Wt^T, fused att logits ----------------
__global__ __launch_bounds__(512, 4) void k_gemm(const unsigned* __restrict__ xb,
                                                 const unsigned short* __restrict__ Wt,
                                                 const float* __restrict__ att_src,
                                                 const float* __restrict__ att_dst,
                                                 unsigned* __restrict__ hb,
                                                 float* __restrict__ a_src,
                                                 float* __restrict__ a_dst, int N) {
    __shared__ unsigned char smA[32768];
    __shared__ unsigned char smB[32768];
    int t = threadIdx.x;
    int w = t >> 6, lane = t & 63;
    int row0 = blockIdx.x * 128;

#pragma unroll
    for (int it = 0; it < 4; ++it) {
        int L = w * 256 + it * 64 + lane;
        int r = L >> 4, c = L & 15;
        int cg = c ^ (r & 7);
        int gr = row0 + r;
        if (gr >= N) gr = N - 1;
        gload16(xb + (size_t)gr * 64 + cg * 4, smA + (size_t)w * 4096 + it * 1024);
        gload16((const unsigned*)Wt + r * 64 + cg * 4, smB + (size_t)w * 4096 + it * 1024);
    }
    __syncthreads();

    int lr = lane & 15, lg = lane >> 4;
    int ar = w * 16 + lr;

    f32x4 acc[8];
#pragma unroll
    for (int j = 0; j < 8; ++j)
#pragma unroll
        for (int q = 0; q < 4; ++q) acc[j][q] = 0.f;

#pragma unroll
    for (int kc = 0; kc < 4; ++kc) {
        bf16x8 av = *(const bf16x8*)&smA[ar * 256 + (((kc * 4 + lg) ^ (ar & 7)) * 16)];
        bf16x8 bv[8];
#pragma unroll
        for (int cf = 0; cf < 8; ++cf) {
            int bc = cf * 16 + lr;
            bv[cf] = *(const bf16x8*)&smB[bc * 256 + (((kc * 4 + lg) ^ (bc & 7)) * 16)];
        }
#pragma unroll
        for (int cf = 0; cf < 8; ++cf)
            acc[cf] = __builtin_amdgcn_mfma_f32_16x16x32_bf16(av, bv[cf], acc[cf], 0, 0, 0);
    }

    float att_s[8], att_d[8];
#pragma unroll
    for (int cf = 0; cf < 8; ++cf) {
        att_s[cf] = att_src[cf * 16 + lr];
        att_d[cf] = att_dst[cf * 16 + lr];
    }
#pragma unroll
    for (int reg = 0; reg < 4; ++reg) {
        int row = row0 + w * 16 + lg * 4 + reg;
        float ps[4], pd[4];
#pragma unroll
        for (int hh = 0; hh < 4; ++hh) {
            ps[hh] = acc[2 * hh][reg] * att_s[2 * hh] + acc[2 * hh + 1][reg] * att_s[2 * hh + 1];
            pd[hh] = acc[2 * hh][reg] * att_d[2 * hh] + acc[2 * hh + 1][reg] * att_d[2 * hh + 1];
        }
#pragma unroll
        for (int m = 1; m <= 8; m <<= 1) {
#pragma unroll
            for (int hh = 0; hh < 4; ++hh) {
                ps[hh] += __shfl_xor(ps[hh], m);
                pd[hh] += __shfl_xor(pd[hh], m);
            }
        }
        if (lr == 0 && row < N) {
            ((float4*)a_src)[row] = float4{ps[0], ps[1], ps[2], ps[3]};
            ((float4*)a_dst)[row] = float4{pd[0], pd[1], pd[2], pd[3]};
        }
    }

    unsigned char* scratch = smA + (size_t)w * 4096;
#pragma unroll
    for (int cf = 0; cf < 8; ++cf) {
#pragma unroll
        for (int reg = 0; reg < 4; ++reg) {
            float v = acc[cf][reg];
            float vo = __shfl_xor(v, 1);
            if (!(lane & 1))
                *(unsigned*)&scratch[(lg * 4 + reg) * 256 + cf * 32 + (lr >> 1) * 4] =
                    bf16pair(v, vo);
        }
    }
#pragma unroll
    for (int q = 0; q < 4; ++q) {
        uint4 u = *(const uint4*)&scratch[q * 1024 + lane * 16];
        int row = row0 + w * 16 + q * 4 + lg;
        if (row < N) ((uint4*)hb)[(size_t)row * 16 + lr] = u;
    }
}

// ---- scan1: padded-degree exclusive scan (per block) + real per-block sum ---
__global__ void k_scan1(const unsigned* __restrict__ deg, unsigned* __restrict__ part,
                        unsigned* __restrict__ blockSums, unsigned* __restrict__ realSums,
                        int N) {
    __shared__ unsigned s[256];
    __shared__ unsigned rs;
    int t = threadIdx.x;
    int i = blockIdx.x * 256 + t;
    unsigned real = (i < N) ? deg[i] : 0u;
    unsigned v = (real + 7u) & ~7u;   // padded degree
    if (t == 0) rs = 0u;
    s[t] = v;
    __syncthreads();
    for (int off = 1; off < 256; off <<= 1) {
        unsigned a = (t >= off) ? s[t - off] : 0u;
        __syncthreads();
        s[t] += a;
        __syncthreads();
    }
    if (i < N) part[i] = s[t] - v;
    if (t == 255) blockSums[blockIdx.x] = s[255];
    unsigned r = real;
#pragma unroll
    for (int m = 1; m <= 32; m <<= 1) r += __shfl_xor(r, m);
    if ((t & 63) == 0) atomicAdd(&rs, r);
    __syncthreads();
    if (t == 0) realSums[blockIdx.x] = rs;
}

__global__ void k_scan2(const unsigned* __restrict__ blockSums,
                        unsigned* __restrict__ blockScan, int NB) {
    __shared__ unsigned s[512];
    int t = threadIdx.x;
    unsigned v = (t < NB) ? blockSums[t] : 0u;
    s[t] = v;
    __syncthreads();
    for (int off = 1; off < 512; off <<= 1) {
        unsigned a = (t >= off) ? s[t - off] : 0u;
        __syncthreads();
        s[t] += a;
        __syncthreads();
    }
    if (t < NB) blockScan[t] = s[t] - v;
}

// ------- pass 1: bucket edges by dst>>8 into ebuf, contiguous per bucket -----
__global__ __launch_bounds__(256) void k_bucket(const int* __restrict__ ei, int E,
                                                const unsigned* __restrict__ blockScan,
                                                unsigned* __restrict__ gcur,
                                                uint2* __restrict__ ebuf,
                                                int NB, int EPB) {
    __shared__ unsigned cnt[512];
    __shared__ unsigned cur2[512];
    __shared__ unsigned lbase[512];
    int t = threadIdx.x;
    int base = blockIdx.x * EPB;
    int lim = base + EPB;
    if (lim > E) lim = E;
    for (int j = t; j < NB; j += 256) { cnt[j] = 0u; cur2[j] = 0u; }
    __syncthreads();
    for (int i = base + t; i < lim; i += 256)
        atomicAdd(&cnt[(unsigned)ei[(size_t)E + i] >> 8], 1u);
    __syncthreads();
    for (int j = t; j < NB; j += 256) {
        unsigned c = cnt[j];
        lbase[j] = c ? (blockScan[j] + atomicAdd(&gcur[j], c)) : 0u;
    }
    __syncthreads();
    for (int i = base + t; i < lim; i += 256) {
        unsigned s = (unsigned)ei[i];
        unsigned d = (unsigned)ei[(size_t)E + i];
        unsigned b = d >> 8;
        unsigned k = atomicAdd(&cur2[b], 1u);
        ebuf[lbase[b] + k] = uint2{s, d};
    }
}

// ------- pass 2: place within bucket, compute p (f16x4), pad to 8 -----------
__global__ __launch_bounds__(256) void k_place(const uint2* __restrict__ ebuf,
                                               const unsigned* __restrict__ blockScan,
                                               const unsigned* __restrict__ realSums,
                                               const unsigned* __restrict__ part,
                                               const unsigned* __restrict__ deg,
                                               const float* __restrict__ a_src,
                                               const float* __restrict__ a_dst,
                                               uint4* __restrict__ csr, int N) {
    __shared__ unsigned curL[256];
    int t = threadIdx.x;
    int b = blockIdx.x;
    curL[t] = 0u;
    __syncthreads();
    unsigned base = blockScan[b];
    unsigned cnt = realSums[b];
    for (unsigned i = t; i < cnt; i += 256) {
        uint2 e = ebuf[base + i];
        unsigned d = e.y;
        unsigned r = atomicAdd(&curL[d & 255u], 1u);
        float4 as = ((const float4*)a_src)[e.x];
        float4 ad = ((const float4*)a_dst)[d];
        float p0 = __expf(lrelu(as.x + ad.x));
        float p1 = __expf(lrelu(as.y + ad.y));
        float p2 = __expf(lrelu(as.z + ad.z));
        float p3 = __expf(lrelu(as.w + ad.w));
        unsigned p01 = __builtin_bit_cast(unsigned, __builtin_amdgcn_cvt_pkrtz(p0, p1));
        unsigned p23 = __builtin_bit_cast(unsigned, __builtin_amdgcn_cvt_pkrtz(p2, p3));
        csr[base + part[d] + r] = uint4{e.x, p01, p23, 0u};
    }
    __syncthreads();
    int n = b * 256 + t;
    if (n < N) {
        unsigned dg = deg[n], dp = (dg + 7u) & ~7u;
        unsigned o = base + part[n];
        for (unsigned j = dg; j < dp; ++j) csr[o + j] = uint4{0u, 0u, 0u, 0u};
    }
}

// ---------------- gather: one wave per dst node, pad-free 8-wide MLP ---------
__global__ __launch_bounds__(256) void k_gather(const unsigned* __restrict__ hb,
                                                const uint4* __restrict__ csr,
                                                const unsigned* __restrict__ part,
                                                const unsigned* __restrict__ blockScan,
                                                const unsigned* __restrict__ deg,
                                                const float* __restrict__ a_src,
                                                const float* __restrict__ a_dst,
                                                const float* __restrict__ bias,
                                                float* __restrict__ out, int N) {
    int n = (int)((blockIdx.x * 256 + threadIdx.x) >> 6);
    int lane = threadIdx.x & 63;
    if (n >= N) return;
    int head = lane >> 4;
    unsigned sh = (head & 1) * 16;
    unsigned off = part[n] + blockScan[n >> 8];
    unsigned endP = off + ((deg[n] + 7u) & ~7u);
    float ax = 0.f, ay = 0.f, dsum = 0.f;
    for (unsigned b = off; b < endP; b += 8) {
        uint4 e[8];
#pragma unroll
        for (int i = 0; i < 8; ++i) e[i] = csr[b + i];
#pragma unroll
        for (int i = 0; i < 8; ++i) {
            unsigned pw = (head & 2) ? e[i].z : e[i].y;
            unsigned short hv = (unsigned short)(pw >> sh);
            float p = (float)__builtin_bit_cast(_Float16, hv);
            unsigned u = hb[e[i].x * 64u + (unsigned)lane];
            ax = fmaf(p, __uint_as_float(u << 16), ax);
            ay = fmaf(p, __uint_as_float(u & 0xFFFF0000u), ay);
            dsum += p;
        }
    }
    // self loop (fp32 p)
    float p_self = __expf(lrelu(a_src[n * 4 + head] + a_dst[n * 4 + head]));
    unsigned us = hb[(unsigned)n * 64u + (unsigned)lane];
    ax = fmaf(p_self, __uint_as_float(us << 16), ax);
    ay = fmaf(p_self, __uint_as_float(us & 0xFFFF0000u), ay);
    dsum += p_self;
    float inv = 1.0f / dsum;
    float2 b2 = ((const float2*)bias)[lane];
    float ox = ax * inv + b2.x;
    float oy = ay * inv + b2.y;
    ox = ox > 0.f ? ox : (__expf(ox) - 1.0f);
    oy = oy > 0.f ? oy : (__expf(oy) - 1.0f);
    ((float2*)out)[(size_t)n * 64 + lane] = float2{ox, oy};
}

extern "C" void kernel_launch(void* const* d_in, const int* in_sizes, int n_in,
                              void* d_out, int out_size, void* d_ws, size_t ws_size,
                              hipStream_t stream) {
    const float* x = (const float*)d_in[0];
    const int* ei = (const int*)d_in[1];
    const float* W = (const float*)d_in[2];
    const float* att_src = (const float*)d_in[3];
    const float* att_dst = (const float*)d_in[4];
    const float* bias = (const float*)d_in[5];
    int N = in_sizes[0] / 128;
    int E = in_sizes[1] / 2;
    int NB = (N + 255) / 256;  // buckets == scan blocks (391)

    char* ws = (char*)d_ws;
    size_t o = 0;
    unsigned* hb = (unsigned*)(ws + o);   o += (size_t)N * 64 * 4;       // 25.6 MB bf16 h
    float* a_src = (float*)(ws + o);      o += (size_t)N * 4 * 4;
    float* a_dst = (float*)(ws + o);      o += (size_t)N * 4 * 4;
    uint4* csr = (uint4*)(ws + o);        o += ((size_t)E + (size_t)N * 8) * 16;  // padded CSR ~37 MB
    unsigned short* Wt = (unsigned short*)(ws + o); o += 128 * 128 * 2;
    unsigned* deg = (unsigned*)(ws + o);  o += (size_t)N * 4;
    unsigned* gcur = (unsigned*)(ws + o); o += 2048;                     // adjacent to deg
    unsigned* part = (unsigned*)(ws + o); o += (size_t)N * 4;
    unsigned* blockSums = (unsigned*)(ws + o); o += 2048;
    unsigned* blockScan = (unsigned*)(ws + o); o += 2048;
    unsigned* realSums = (unsigned*)(ws + o);  o += 2048;

    // scratch inside d_out (51.2 MB): xb in lower half, ebuf above it.
    // Both dead before k_gather rewrites d_out.
    unsigned* xb = (unsigned*)d_out;                                   // 25.6 MB
    uint2* ebuf = (uint2*)((char*)d_out + (size_t)N * 256);            // 12.8 MB

    hipMemsetAsync(deg, 0, (size_t)N * 4 + 2048, stream);  // deg + gcur

    k_prep<<<2048, 256, 0, stream>>>(x, W, ei, deg, xb, Wt, N, E);
    k_gemm<<<(N + 127) / 128, 512, 0, stream>>>(xb, Wt, att_src, att_dst, hb, a_src, a_dst, N);
    k_scan1<<<NB, 256, 0, stream>>>(deg, part, blockSums, realSums, N);
    k_scan2<<<1, 512, 0, stream>>>(blockSums, blockScan, NB);
    int EPB = 16384;
    k_bucket<<<(E + EPB - 1) / EPB, 256, 0, stream>>>(ei, E, blockScan, gcur, ebuf, NB, EPB);
    k_place<<<NB, 256, 0, stream>>>(ebuf, blockScan, realSums, part, deg, a_src, a_dst, csr, N);
    k_gather<<<(N * 64 + 255) / 256, 256, 0, stream>>>(hb, csr, part, blockScan, deg,
                                                       a_src, a_dst, bias, (float*)d_out, N);
}

// Round 10
// 235.824 us; speedup vs baseline: 1.1497x; 1.1497x over previous
//
#include <hip/hip_runtime.h>
#include <hip/hip_bf16.h>

#define NEG_SLOPE 0.2f

typedef __attribute__((ext_vector_type(8))) short bf16x8;
typedef __attribute__((ext_vector_type(4))) float f32x4;

__device__ __forceinline__ float lrelu(float v) { return v > 0.0f ? v : NEG_SLOPE * v; }

__device__ __forceinline__ unsigned bf16pair(float a, float b) {
    unsigned ua = __float_as_uint(a), ub = __float_as_uint(b);
    ua = (ua + 0x7FFFu + ((ua >> 16) & 1u)) >> 16;
    ub = (ub + 0x7FFFu + ((ub >> 16) & 1u)) >> 16;
    return ua | (ub << 16);
}

__device__ __forceinline__ void gload16(const void* g, void* l) {
    __builtin_amdgcn_global_load_lds(
        (const __attribute__((address_space(1))) unsigned*)g,
        (__attribute__((address_space(3))) unsigned*)l, 16, 0, 0);
}

// ---------------- prep: x->xb bf16, W->Wt bf16 transposed, deg histogram ----
__global__ __launch_bounds__(256) void k_prep(const float* __restrict__ x,
                                              const float* __restrict__ W,
                                              const int* __restrict__ ei,
                                              unsigned* __restrict__ deg,
                                              unsigned* __restrict__ xb,
                                              unsigned short* __restrict__ Wt,
                                              int N, int E) {
    int gid = blockIdx.x * 256 + threadIdx.x;
    int gsz = gridDim.x * 256;
    int nf4 = N * 32;
    for (int i = gid; i < nf4; i += gsz) {
        float4 f = ((const float4*)x)[i];
        uint2 u;
        u.x = bf16pair(f.x, f.y);
        u.y = bf16pair(f.z, f.w);
        ((uint2*)xb)[i] = u;
    }
    if (gid < 16384) {
        int col = gid >> 7, k = gid & 127;
        float v = W[(size_t)k * 128 + col];
        unsigned u = __float_as_uint(v);
        u = (u + 0x7FFFu + ((u >> 16) & 1u)) >> 16;
        Wt[col * 128 + k] = (unsigned short)u;
    }
    for (int i = gid; i < E; i += gsz)
        atomicAdd(&deg[ei[(size_t)E + i]], 1u);
}

// ---- scan1: per-block exclusive scan + scatter-add block total to later blocks
__global__ void k_scan1(const unsigned* __restrict__ deg, unsigned* __restrict__ part,
                        unsigned* __restrict__ blockSums, unsigned* __restrict__ blockScan,
                        int N, int NB) {
    __shared__ unsigned s[256];
    int t = threadIdx.x;
    int b = blockIdx.x;
    int i = b * 256 + t;
    unsigned v = (i < N) ? deg[i] : 0u;
    s[t] = v;
    __syncthreads();
    for (int off = 1; off < 256; off <<= 1) {
        unsigned a = (t >= off) ? s[t - off] : 0u;
        __syncthreads();
        s[t] += a;
        __syncthreads();
    }
    if (i < N) part[i] = s[t] - v;
    unsigned total = s[255];
    if (t == 0) blockSums[b] = total;
    // blockScan[j] += total for all j > b (blockScan pre-zeroed by memset)
    for (int j = b + 1 + t; j < NB; j += 256)
        atomicAdd(&blockScan[j], total);
}

// ---------------- fused: bucket blocks (first NBK) + gemm blocks ------------
__global__ __launch_bounds__(512) void k_gembk(const unsigned* __restrict__ xb,
                                               const unsigned short* __restrict__ Wt,
                                               const float* __restrict__ att_src,
                                               const float* __restrict__ att_dst,
                                               unsigned* __restrict__ hb,
                                               float* __restrict__ a_src,
                                               float* __restrict__ a_dst,
                                               const int* __restrict__ ei,
                                               const unsigned* __restrict__ blockScan,
                                               unsigned* __restrict__ gcur,
                                               uint2* __restrict__ ebuf,
                                               int N, int E, int NB, int NBK, int EPB) {
    __shared__ unsigned char sm[65536];
    int t = threadIdx.x;

    if ((int)blockIdx.x < NBK) {
        // ---------------- bucket path ----------------
        unsigned* cnt = (unsigned*)sm;
        unsigned* cur2 = (unsigned*)(sm + 2048);
        unsigned* lbase = (unsigned*)(sm + 4096);
        int base = blockIdx.x * EPB;
        int lim = base + EPB;
        if (lim > E) lim = E;
        for (int j = t; j < NB; j += 512) { cnt[j] = 0u; cur2[j] = 0u; }
        __syncthreads();
        for (int i = base + t; i < lim; i += 512)
            atomicAdd(&cnt[(unsigned)ei[(size_t)E + i] >> 8], 1u);
        __syncthreads();
        for (int j = t; j < NB; j += 512) {
            unsigned c = cnt[j];
            lbase[j] = c ? (blockScan[j] + atomicAdd(&gcur[j], c)) : 0u;
        }
        __syncthreads();
        for (int i = base + t; i < lim; i += 512) {
            unsigned s = (unsigned)ei[i];
            unsigned d = (unsigned)ei[(size_t)E + i];
            unsigned b = d >> 8;
            unsigned k = atomicAdd(&cur2[b], 1u);
            ebuf[lbase[b] + k] = uint2{s, d};
        }
        return;
    }

    // ---------------- gemm path ----------------
    unsigned char* smA = sm;
    unsigned char* smB = sm + 32768;
    int w = t >> 6, lane = t & 63;
    int row0 = ((int)blockIdx.x - NBK) * 128;

#pragma unroll
    for (int it = 0; it < 4; ++it) {
        int L = w * 256 + it * 64 + lane;
        int r = L >> 4, c = L & 15;
        int cg = c ^ (r & 7);
        int gr = row0 + r;
        if (gr >= N) gr = N - 1;
        gload16(xb + (size_t)gr * 64 + cg * 4, smA + (size_t)w * 4096 + it * 1024);
        gload16((const unsigned*)Wt + r * 64 + cg * 4, smB + (size_t)w * 4096 + it * 1024);
    }
    __syncthreads();

    int lr = lane & 15, lg = lane >> 4;
    int ar = w * 16 + lr;

    f32x4 acc[8];
#pragma unroll
    for (int j = 0; j < 8; ++j)
#pragma unroll
        for (int q = 0; q < 4; ++q) acc[j][q] = 0.f;

#pragma unroll
    for (int kc = 0; kc < 4; ++kc) {
        bf16x8 av = *(const bf16x8*)&smA[ar * 256 + (((kc * 4 + lg) ^ (ar & 7)) * 16)];
        bf16x8 bv[8];
#pragma unroll
        for (int cf = 0; cf < 8; ++cf) {
            int bc = cf * 16 + lr;
            bv[cf] = *(const bf16x8*)&smB[bc * 256 + (((kc * 4 + lg) ^ (bc & 7)) * 16)];
        }
#pragma unroll
        for (int cf = 0; cf < 8; ++cf)
            acc[cf] = __builtin_amdgcn_mfma_f32_16x16x32_bf16(av, bv[cf], acc[cf], 0, 0, 0);
    }

    float att_s[8], att_d[8];
#pragma unroll
    for (int cf = 0; cf < 8; ++cf) {
        att_s[cf] = att_src[cf * 16 + lr];
        att_d[cf] = att_dst[cf * 16 + lr];
    }
#pragma unroll
    for (int reg = 0; reg < 4; ++reg) {
        int row = row0 + w * 16 + lg * 4 + reg;
        float ps[4], pd[4];
#pragma unroll
        for (int hh = 0; hh < 4; ++hh) {
            ps[hh] = acc[2 * hh][reg] * att_s[2 * hh] + acc[2 * hh + 1][reg] * att_s[2 * hh + 1];
            pd[hh] = acc[2 * hh][reg] * att_d[2 * hh] + acc[2 * hh + 1][reg] * att_d[2 * hh + 1];
        }
#pragma unroll
        for (int m = 1; m <= 8; m <<= 1) {
#pragma unroll
            for (int hh = 0; hh < 4; ++hh) {
                ps[hh] += __shfl_xor(ps[hh], m);
                pd[hh] += __shfl_xor(pd[hh], m);
            }
        }
        if (lr == 0 && row < N) {
            ((float4*)a_src)[row] = float4{ps[0], ps[1], ps[2], ps[3]};
            ((float4*)a_dst)[row] = float4{pd[0], pd[1], pd[2], pd[3]};
        }
    }

    unsigned char* scratch = smA + (size_t)w * 4096;
#pragma unroll
    for (int cf = 0; cf < 8; ++cf) {
#pragma unroll
        for (int reg = 0; reg < 4; ++reg) {
            float v = acc[cf][reg];
            float vo = __shfl_xor(v, 1);
            if (!(lane & 1))
                *(unsigned*)&scratch[(lg * 4 + reg) * 256 + cf * 32 + (lr >> 1) * 4] =
                    bf16pair(v, vo);
        }
    }
#pragma unroll
    for (int q = 0; q < 4; ++q) {
        uint4 u = *(const uint4*)&scratch[q * 1024 + lane * 16];
        int row = row0 + w * 16 + q * 4 + lg;
        if (row < N) ((uint4*)hb)[(size_t)row * 16 + lr] = u;
    }
}

// ------- place within bucket: compute p (f16x4), write 16B CSR entries ------
__global__ __launch_bounds__(256) void k_place(const uint2* __restrict__ ebuf,
                                               const unsigned* __restrict__ blockScan,
                                               const unsigned* __restrict__ blockSums,
                                               const unsigned* __restrict__ part,
                                               const float* __restrict__ a_src,
                                               const float* __restrict__ a_dst,
                                               uint4* __restrict__ csr) {
    __shared__ unsigned curL[256];
    int t = threadIdx.x;
    int b = blockIdx.x;
    curL[t] = 0u;
    __syncthreads();
    unsigned base = blockScan[b];
    unsigned cnt = blockSums[b];
    for (unsigned i = t; i < cnt; i += 256) {
        uint2 e = ebuf[base + i];
        unsigned d = e.y;
        unsigned r = atomicAdd(&curL[d & 255u], 1u);
        float4 as = ((const float4*)a_src)[e.x];
        float4 ad = ((const float4*)a_dst)[d];
        float p0 = __expf(lrelu(as.x + ad.x));
        float p1 = __expf(lrelu(as.y + ad.y));
        float p2 = __expf(lrelu(as.z + ad.z));
        float p3 = __expf(lrelu(as.w + ad.w));
        unsigned p01 = __builtin_bit_cast(unsigned, __builtin_amdgcn_cvt_pkrtz(p0, p1));
        unsigned p23 = __builtin_bit_cast(unsigned, __builtin_amdgcn_cvt_pkrtz(p2, p3));
        csr[base + part[d] + r] = uint4{e.x, p01, p23, 0u};
    }
}

// ---------------- gather: one wave per dst node, clamped 8-wide MLP ----------
__global__ __launch_bounds__(256) void k_gather(const unsigned* __restrict__ hb,
                                                const uint4* __restrict__ csr,
                                                const unsigned* __restrict__ part,
                                                const unsigned* __restrict__ blockScan,
                                                const unsigned* __restrict__ deg,
                                                const float* __restrict__ a_src,
                                                const float* __restrict__ a_dst,
                                                const float* __restrict__ bias,
                                                float* __restrict__ out, int N) {
    int n = (int)((blockIdx.x * 256 + threadIdx.x) >> 6);
    int lane = threadIdx.x & 63;
    if (n >= N) return;
    int head = lane >> 4;
    unsigned sh = (head & 1) * 16;
    unsigned off = part[n] + blockScan[n >> 8];
    unsigned end = off + deg[n];
    float ax = 0.f, ay = 0.f, dsum = 0.f;
    for (unsigned b = off; b < end; b += 8) {
        uint4 e[8];
#pragma unroll
        for (int i = 0; i < 8; ++i) {
            unsigned idx = b + i;
            if (idx >= end) idx = end - 1;
            e[i] = csr[idx];
        }
#pragma unroll
        for (int i = 0; i < 8; ++i) {
            unsigned pw = (head & 2) ? e[i].z : e[i].y;
            unsigned short hv = (unsigned short)(pw >> sh);
            float p = (float)__builtin_bit_cast(_Float16, hv);
            p = (b + i < end) ? p : 0.f;
            unsigned u = hb[e[i].x * 64u + (unsigned)lane];
            ax = fmaf(p, __uint_as_float(u << 16), ax);
            ay = fmaf(p, __uint_as_float(u & 0xFFFF0000u), ay);
            dsum += p;
        }
    }
    float p_self = __expf(lrelu(a_src[n * 4 + head] + a_dst[n * 4 + head]));
    unsigned us = hb[(unsigned)n * 64u + (unsigned)lane];
    ax = fmaf(p_self, __uint_as_float(us << 16), ax);
    ay = fmaf(p_self, __uint_as_float(us & 0xFFFF0000u), ay);
    dsum += p_self;
    float inv = 1.0f / dsum;
    float2 b2 = ((const float2*)bias)[lane];
    float ox = ax * inv + b2.x;
    float oy = ay * inv + b2.y;
    ox = ox > 0.f ? ox : (__expf(ox) - 1.0f);
    oy = oy > 0.f ? oy : (__expf(oy) - 1.0f);
    ((float2*)out)[(size_t)n * 64 + lane] = float2{ox, oy};
}

extern "C" void kernel_launch(void* const* d_in, const int* in_sizes, int n_in,
                              void* d_out, int out_size, void* d_ws, size_t ws_size,
                              hipStream_t stream) {
    const float* x = (const float*)d_in[0];
    const int* ei = (const int*)d_in[1];
    const float* W = (const float*)d_in[2];
    const float* att_src = (const float*)d_in[3];
    const float* att_dst = (const float*)d_in[4];
    const float* bias = (const float*)d_in[5];
    int N = in_sizes[0] / 128;
    int E = in_sizes[1] / 2;
    int NB = (N + 255) / 256;  // 391 buckets

    char* ws = (char*)d_ws;
    size_t o = 0;
    unsigned* hb = (unsigned*)(ws + o);   o += (size_t)N * 64 * 4;   // 25.6 MB
    float* a_src = (float*)(ws + o);      o += (size_t)N * 4 * 4;
    float* a_dst = (float*)(ws + o);      o += (size_t)N * 4 * 4;
    uint4* csr = (uint4*)(ws + o);        o += (size_t)E * 16;       // 25.6 MB
    unsigned short* Wt = (unsigned short*)(ws + o); o += 128 * 128 * 2;
    unsigned* deg = (unsigned*)(ws + o);  o += (size_t)N * 4;        // ---- zeroed region
    unsigned* gcur = (unsigned*)(ws + o); o += 2048;
    unsigned* blockScan = (unsigned*)(ws + o); o += 2048;            // ---- end zeroed
    unsigned* part = (unsigned*)(ws + o); o += (size_t)N * 4;
    unsigned* blockSums = (unsigned*)(ws + o); o += 2048;

    // scratch inside d_out (51.2 MB): xb lower, ebuf above; both dead before
    // k_gather rewrites d_out.
    unsigned* xb = (unsigned*)d_out;                          // 25.6 MB
    uint2* ebuf = (uint2*)((char*)d_out + (size_t)N * 256);   // 12.8 MB

    hipMemsetAsync(deg, 0, (size_t)N * 4 + 4096, stream);  // deg + gcur + blockScan

    k_prep<<<2048, 256, 0, stream>>>(x, W, ei, deg, xb, Wt, N, E);
    k_scan1<<<NB, 256, 0, stream>>>(deg, part, blockSums, blockScan, N, NB);
    int EPB = 16384;
    int NBK = (E + EPB - 1) / EPB;  // 98 bucket blocks
    int nbG = (N + 127) / 128;      // 782 gemm blocks
    k_gembk<<<NBK + nbG, 512, 0, stream>>>(xb, Wt, att_src, att_dst, hb, a_src, a_dst,
                                           ei, blockScan, gcur, ebuf, N, E, NB, NBK, EPB);
    k_place<<<NB, 256, 0, stream>>>(ebuf, blockScan, blockSums, part, a_src, a_dst, csr);
    k_gather<<<(N * 64 + 255) / 256, 256, 0, stream>>>(hb, csr, part, blockScan, deg,
                                                       a_src, a_dst, bias, (float*)d_out, N);
}